// Round 1
// baseline (5897.638 us; speedup 1.0000x reference)
//
#include <hip/hip_runtime.h>

#define SEQL 512
#define BSZ  32
#define HID  1024
#define KDIM 1024
#define NWG_SCAN 16
#define HN_OFF 16777216   // 32*512*1024

// ws layout (bytes)
#define XPROJ_OFF 0u
#define HSB_OFF   67108864u      // 512*32*1024*4
#define HZ_OFF    100663296u    // + 512*32*1024*2
#define BAR_OFF   100728832u    // + 32*1024*2

using f32x4  = __attribute__((ext_vector_type(4))) float;
using u16x8  = __attribute__((ext_vector_type(8))) unsigned short;
using bf16x8 = __attribute__((ext_vector_type(8))) __bf16;

__device__ __forceinline__ f32x4 mfma16(u16x8 a, u16x8 b, f32x4 c) {
  return __builtin_amdgcn_mfma_f32_16x16x32_bf16(
      __builtin_bit_cast(bf16x8, a), __builtin_bit_cast(bf16x8, b), c, 0, 0, 0);
}

__device__ __forceinline__ unsigned short f2bf(float f) {
  unsigned u = __builtin_bit_cast(unsigned, f);
  u += 0x7fffu + ((u >> 16) & 1u);
  return (unsigned short)(u >> 16);
}

__device__ __forceinline__ float tanh_fast(float x) {
  float cx = fminf(fmaxf(x, -15.f), 15.f);
  float e = __expf(2.f * cx);
  return __fdividef(e - 1.f, e + 1.f);
}

// -------- init: zero h0 buffer + barrier words --------
__global__ void init_kernel(unsigned int* hz, int* bar) {
  int i = blockIdx.x * 256 + threadIdx.x;   // grid 64 * 256 = 16384 uints = 64KB
  hz[i] = 0u;
  if (blockIdx.x == 0) bar[threadIdx.x] = 0;
}

// -------- device-scope generation barrier over NWG workgroups --------
__device__ __forceinline__ void grid_barrier(int* ctr, int* gen, int nwg, int it) {
  __syncthreads();
  if (threadIdx.x == 0) {
    __threadfence();
    int prev = __hip_atomic_fetch_add(ctr, 1, __ATOMIC_RELAXED, __HIP_MEMORY_SCOPE_AGENT);
    if (prev == nwg - 1) {
      __hip_atomic_store(ctr, 0, __ATOMIC_RELAXED, __HIP_MEMORY_SCOPE_AGENT);
      __hip_atomic_store(gen, it + 1, __ATOMIC_RELEASE, __HIP_MEMORY_SCOPE_AGENT);
    } else {
      while (__hip_atomic_load(gen, __ATOMIC_ACQUIRE, __HIP_MEMORY_SCOPE_AGENT) <= it) {
        __builtin_amdgcn_s_sleep(1);
      }
    }
    __threadfence();
  }
  __syncthreads();
}

// -------- xproj GEMM: out[M=16384][1024] = A[M][K]*W^T + (bih+bhh) --------
// L0: A = x (f32, [bs][seq][in] -> row remap), else A = hsb (bf16, rows = s*32+b)
template<bool L0>
__global__ __launch_bounds__(256, 2)
void xproj_gemm(const void* __restrict__ Aptr,
                const float* __restrict__ W,
                const float* __restrict__ bih,
                const float* __restrict__ bhh,
                float* __restrict__ out)
{
  __shared__ unsigned short sA[128 * 32];
  __shared__ unsigned short sB[128 * 32];
  const int tid  = threadIdx.x;
  const int lane = tid & 63;
  const int wave = tid >> 6;
  const int wm = wave >> 1, wn = wave & 1;
  const int bm = blockIdx.x >> 3;
  const int bn = blockIdx.x & 7;
  const int l15 = lane & 15;
  const int koff = (lane >> 4) * 8;
  const int srow = tid >> 2;         // 0..63
  const int skc  = (tid & 3) * 8;    // 0,8,16,24

  f32x4 acc[4][4];
#pragma unroll
  for (int i = 0; i < 4; ++i)
#pragma unroll
    for (int j = 0; j < 4; ++j) acc[i][j] = (f32x4)0.f;

  for (int k0 = 0; k0 < KDIM; k0 += 32) {
#pragma unroll
    for (int r = 0; r < 2; ++r) {
      int row = r * 64 + srow;
      int Mrow = bm * 128 + row;
      u16x8 av;
      if (L0) {
        const float* src = (const float*)Aptr +
            ((size_t)(Mrow & 31) * SEQL + (Mrow >> 5)) * KDIM + k0 + skc;
        float4 a = ((const float4*)src)[0];
        float4 b = ((const float4*)src)[1];
        av[0]=f2bf(a.x); av[1]=f2bf(a.y); av[2]=f2bf(a.z); av[3]=f2bf(a.w);
        av[4]=f2bf(b.x); av[5]=f2bf(b.y); av[6]=f2bf(b.z); av[7]=f2bf(b.w);
      } else {
        av = *(const u16x8*)((const unsigned short*)Aptr + (size_t)Mrow * KDIM + k0 + skc);
      }
      *(u16x8*)&sA[row * 32 + skc] = av;

      const float* wsrc = W + (size_t)(bn * 128 + row) * KDIM + k0 + skc;
      float4 wa = ((const float4*)wsrc)[0];
      float4 wb = ((const float4*)wsrc)[1];
      u16x8 wv;
      wv[0]=f2bf(wa.x); wv[1]=f2bf(wa.y); wv[2]=f2bf(wa.z); wv[3]=f2bf(wa.w);
      wv[4]=f2bf(wb.x); wv[5]=f2bf(wb.y); wv[6]=f2bf(wb.z); wv[7]=f2bf(wb.w);
      *(u16x8*)&sB[row * 32 + skc] = wv;
    }
    __syncthreads();

    u16x8 af[4], bfr[4];
#pragma unroll
    for (int mt = 0; mt < 4; ++mt)
      af[mt] = *(const u16x8*)&sA[(wm * 64 + mt * 16 + l15) * 32 + koff];
#pragma unroll
    for (int nt = 0; nt < 4; ++nt)
      bfr[nt] = *(const u16x8*)&sB[(wn * 64 + nt * 16 + l15) * 32 + koff];
#pragma unroll
    for (int mt = 0; mt < 4; ++mt)
#pragma unroll
      for (int nt = 0; nt < 4; ++nt)
        acc[mt][nt] = mfma16(af[mt], bfr[nt], acc[mt][nt]);
    __syncthreads();
  }

#pragma unroll
  for (int nt = 0; nt < 4; ++nt) {
    int colg = bn * 128 + wn * 64 + nt * 16 + l15;
    float bias = bih[colg] + bhh[colg];
#pragma unroll
    for (int mt = 0; mt < 4; ++mt) {
#pragma unroll
      for (int i = 0; i < 4; ++i) {
        int rowg = bm * 128 + wm * 64 + mt * 16 + (lane >> 4) * 4 + i;
        out[(size_t)rowg * HID + colg] = acc[mt][nt][i] + bias;
      }
    }
  }
}

// -------- persistent recurrent scan --------
// 16 WGs x 256 thr. WG owns 64 output cols; wave w owns K-slice [w*256, w*256+256).
// W_hh slice lives in VGPRs (bf16 frags) for the whole scan.
template<int LAYER>
__global__ __launch_bounds__(256, 1)
void rnn_scan(const float* __restrict__ xproj,      // [seq][bs][H] f32
              const float* __restrict__ whh,        // [H][H] f32 (this layer)
              unsigned short* __restrict__ hsb,     // [seq][bs][H] bf16 (h states)
              const unsigned short* __restrict__ hz,// [bs][H] bf16 zeros
              float* __restrict__ out,              // d_out
              int* ctr, int* gen)
{
  const int tid  = threadIdx.x;
  const int lane = tid & 63;
  const int wave = tid >> 6;
  const int l15  = lane & 15;
  const int l4   = lane >> 4;
  const int col0 = blockIdx.x * 64;
  const int kbase = wave * 256;

  __shared__ float red[4][32][68];   // padded: conflict-light, 16B-aligned rows

  // persistent W_hh fragments: [ntile][kstep]
  u16x8 Bf[4][8];
#pragma unroll
  for (int nt = 0; nt < 4; ++nt) {
#pragma unroll
    for (int ks = 0; ks < 8; ++ks) {
      const float* src = whh + (size_t)(col0 + nt * 16 + l15) * KDIM + kbase + ks * 32 + l4 * 8;
      float4 a = ((const float4*)src)[0];
      float4 b = ((const float4*)src)[1];
      u16x8 v;
      v[0]=f2bf(a.x); v[1]=f2bf(a.y); v[2]=f2bf(a.z); v[3]=f2bf(a.w);
      v[4]=f2bf(b.x); v[5]=f2bf(b.y); v[6]=f2bf(b.z); v[7]=f2bf(b.w);
      Bf[nt][ks] = v;
    }
  }

  const int frow = tid >> 3;         // 0..31  (batch row in finish phase)
  const int fcb  = (tid & 7) * 8;    // 0..56  (col offset within WG slice)

  // prefetch xproj for t=0
  const float* xpp = xproj + (size_t)frow * HID + col0 + fcb;
  float4 xp0 = ((const float4*)xpp)[0];
  float4 xp1 = ((const float4*)xpp)[1];

  for (int t = 0; t < SEQL; ++t) {
    const unsigned short* hp = (t == 0) ? hz : (hsb + (size_t)(t - 1) * (BSZ * HID));

    u16x8 Af[2][8];
#pragma unroll
    for (int m = 0; m < 2; ++m)
#pragma unroll
      for (int ks = 0; ks < 8; ++ks)
        Af[m][ks] = *(const u16x8*)(hp + (size_t)(m * 16 + l15) * HID + kbase + ks * 32 + l4 * 8);

    f32x4 acc[2][4];
#pragma unroll
    for (int m = 0; m < 2; ++m)
#pragma unroll
      for (int n = 0; n < 4; ++n)
        acc[m][n] = (f32x4)0.f;

#pragma unroll
    for (int ks = 0; ks < 8; ++ks)
#pragma unroll
      for (int m = 0; m < 2; ++m)
#pragma unroll
        for (int n = 0; n < 4; ++n)
          acc[m][n] = mfma16(Af[m][ks], Bf[n][ks], acc[m][n]);

    // partials -> LDS
#pragma unroll
    for (int m = 0; m < 2; ++m)
#pragma unroll
      for (int n = 0; n < 4; ++n)
#pragma unroll
        for (int i = 0; i < 4; ++i)
          red[wave][m * 16 + l4 * 4 + i][n * 16 + l15] = acc[m][n][i];

    __syncthreads();

    // finish: reduce 4 waves, +xproj, tanh, write
    float sv[8];
#pragma unroll
    for (int jj = 0; jj < 2; ++jj) {
      float4 r0 = *(const float4*)&red[0][frow][fcb + jj * 4];
      float4 r1 = *(const float4*)&red[1][frow][fcb + jj * 4];
      float4 r2 = *(const float4*)&red[2][frow][fcb + jj * 4];
      float4 r3 = *(const float4*)&red[3][frow][fcb + jj * 4];
      sv[jj*4+0] = r0.x + r1.x + r2.x + r3.x;
      sv[jj*4+1] = r0.y + r1.y + r2.y + r3.y;
      sv[jj*4+2] = r0.z + r1.z + r2.z + r3.z;
      sv[jj*4+3] = r0.w + r1.w + r2.w + r3.w;
    }
    float xv[8] = {xp0.x, xp0.y, xp0.z, xp0.w, xp1.x, xp1.y, xp1.z, xp1.w};
    float hv[8];
#pragma unroll
    for (int j = 0; j < 8; ++j) hv[j] = tanh_fast(sv[j] + xv[j]);

    u16x8 hb;
#pragma unroll
    for (int j = 0; j < 8; ++j) hb[j] = f2bf(hv[j]);
    *(u16x8*)(hsb + (size_t)t * (BSZ * HID) + (size_t)frow * HID + col0 + fcb) = hb;

    if (LAYER == 1) {
      float* o = out + ((size_t)frow * SEQL + t) * HID + col0 + fcb;
      ((float4*)o)[0] = make_float4(hv[0], hv[1], hv[2], hv[3]);
      ((float4*)o)[1] = make_float4(hv[4], hv[5], hv[6], hv[7]);
    }
    if (t == SEQL - 1) {
      float* o = out + HN_OFF + LAYER * (BSZ * HID) + (size_t)frow * HID + col0 + fcb;
      ((float4*)o)[0] = make_float4(hv[0], hv[1], hv[2], hv[3]);
      ((float4*)o)[1] = make_float4(hv[4], hv[5], hv[6], hv[7]);
    }

    // prefetch next step's xproj before the barrier (hides under spin)
    {
      int tn = (t + 1 < SEQL) ? t + 1 : t;
      const float* nxt = xproj + ((size_t)tn * BSZ + frow) * HID + col0 + fcb;
      xp0 = ((const float4*)nxt)[0];
      xp1 = ((const float4*)nxt)[1];
    }

    grid_barrier(ctr, gen, NWG_SCAN, t);
  }
}

extern "C" void kernel_launch(void* const* d_in, const int* in_sizes, int n_in,
                              void* d_out, int out_size, void* d_ws, size_t ws_size,
                              hipStream_t stream) {
  const float* x    = (const float*)d_in[0];
  const float* w_ih = (const float*)d_in[1];
  const float* w_hh = (const float*)d_in[2];
  const float* b_ih = (const float*)d_in[3];
  const float* b_hh = (const float*)d_in[4];
  float* out = (float*)d_out;
  char* ws = (char*)d_ws;

  float* xproj          = (float*)(ws + XPROJ_OFF);
  unsigned short* hsb   = (unsigned short*)(ws + HSB_OFF);
  unsigned short* hz    = (unsigned short*)(ws + HZ_OFF);
  int* bar              = (int*)(ws + BAR_OFF);

  init_kernel<<<64, 256, 0, stream>>>((unsigned int*)hz, bar);

  // layer 0
  xproj_gemm<true><<<1024, 256, 0, stream>>>((const void*)x, w_ih, b_ih, b_hh, xproj);
  rnn_scan<0><<<NWG_SCAN, 256, 0, stream>>>(xproj, w_hh, hsb, hz, out, bar + 0, bar + 32);

  // layer 1
  xproj_gemm<false><<<1024, 256, 0, stream>>>((const void*)hsb,
      w_ih + (size_t)HID * KDIM, b_ih + HID, b_hh + HID, xproj);
  rnn_scan<1><<<NWG_SCAN, 256, 0, stream>>>(xproj, w_hh + (size_t)HID * HID, hsb, hz, out,
      bar + 64, bar + 96);
}

// Round 2
// 4767.671 us; speedup vs baseline: 1.2370x; 1.2370x over previous
//
#include <hip/hip_runtime.h>

#define SEQL 512
#define BSZ  32
#define HID  1024
#define NWG  48
#define HN_OFF 16777216   // 32*512*1024

// ws layout (bytes): xps f32 [512][32][1024] @0 (64MB); h0b bf16 @64MB (32MB); ctr @96MB
#define XPS_OFF 0u
#define H0B_OFF 67108864u
#define CTR_OFF 100663296u

using f32x4  = __attribute__((ext_vector_type(4))) float;
using u16x8  = __attribute__((ext_vector_type(8))) unsigned short;
using bf16x8 = __attribute__((ext_vector_type(8))) __bf16;
using u64x2  = __attribute__((ext_vector_type(2))) unsigned long long;

__device__ __forceinline__ f32x4 mfma16(u16x8 a, u16x8 b, f32x4 c) {
  return __builtin_amdgcn_mfma_f32_16x16x32_bf16(
      __builtin_bit_cast(bf16x8, a), __builtin_bit_cast(bf16x8, b), c, 0, 0, 0);
}

__device__ __forceinline__ unsigned short f2bf(float f) {
  unsigned u = __builtin_bit_cast(unsigned, f);
  u += 0x7fffu + ((u >> 16) & 1u);
  return (unsigned short)(u >> 16);
}

__device__ __forceinline__ float tanh_fast(float x) {
  float cx = fminf(fmaxf(x, -15.f), 15.f);
  float e = __expf(2.f * cx);
  return __fdividef(e - 1.f, e + 1.f);
}

// device-scope write-through store / L2-bypass load (no fences needed)
__device__ __forceinline__ void stwt(unsigned long long* p, unsigned long long v) {
  __hip_atomic_store(p, v, __ATOMIC_RELAXED, __HIP_MEMORY_SCOPE_AGENT);
}
__device__ __forceinline__ unsigned long long ldat(const unsigned long long* p) {
  return __hip_atomic_load(p, __ATOMIC_RELAXED, __HIP_MEMORY_SCOPE_AGENT);
}

__global__ void init_kernel(unsigned int* ctr) {
  if (threadIdx.x < 16) ctr[threadIdx.x] = 0u;
}

// fence-free monotonic-counter barrier. Writers must be write-through atomics.
__device__ __forceinline__ void arrive_wait(unsigned int* ctr, unsigned int target) {
  asm volatile("s_waitcnt vmcnt(0)" ::: "memory");  // per-wave: drain WT stores to LLC
  __syncthreads();                                   // all waves drained
  if (threadIdx.x == 0)
    __hip_atomic_fetch_add(ctr, 1u, __ATOMIC_RELAXED, __HIP_MEMORY_SCOPE_AGENT);
  if ((threadIdx.x & 63) == 0) {
    while (__hip_atomic_load(ctr, __ATOMIC_RELAXED, __HIP_MEMORY_SCOPE_AGENT) < target)
      __builtin_amdgcn_s_sleep(1);
  }
  __syncthreads();
  asm volatile("" ::: "memory");
}

// -------- xproj GEMM (layer 0): xps[s*32+b][h] = x[b][s][:]·W_ih0^T + b_ih0 + b_hh0
__global__ __launch_bounds__(256, 2)
void xproj_gemm(const float* __restrict__ X,
                const float* __restrict__ W,
                const float* __restrict__ bih,
                const float* __restrict__ bhh,
                float* __restrict__ out)
{
  __shared__ unsigned short sA[128 * 32];
  __shared__ unsigned short sB[128 * 32];
  const int tid  = threadIdx.x;
  const int lane = tid & 63;
  const int wave = tid >> 6;
  const int wm = wave >> 1, wn = wave & 1;
  const int bm = blockIdx.x >> 3;
  const int bn = blockIdx.x & 7;
  const int l15 = lane & 15;
  const int koff = (lane >> 4) * 8;
  const int srow = tid >> 2;
  const int skc  = (tid & 3) * 8;

  f32x4 acc[4][4];
#pragma unroll
  for (int i = 0; i < 4; ++i)
#pragma unroll
    for (int j = 0; j < 4; ++j) acc[i][j] = (f32x4)0.f;

  for (int k0 = 0; k0 < HID; k0 += 32) {
#pragma unroll
    for (int r = 0; r < 2; ++r) {
      int row = r * 64 + srow;
      int Mrow = bm * 128 + row;
      const float* src = X + ((size_t)(Mrow & 31) * SEQL + (Mrow >> 5)) * HID + k0 + skc;
      float4 a = ((const float4*)src)[0];
      float4 b = ((const float4*)src)[1];
      u16x8 av;
      av[0]=f2bf(a.x); av[1]=f2bf(a.y); av[2]=f2bf(a.z); av[3]=f2bf(a.w);
      av[4]=f2bf(b.x); av[5]=f2bf(b.y); av[6]=f2bf(b.z); av[7]=f2bf(b.w);
      *(u16x8*)&sA[row * 32 + skc] = av;

      const float* wsrc = W + (size_t)(bn * 128 + row) * HID + k0 + skc;
      float4 wa = ((const float4*)wsrc)[0];
      float4 wb = ((const float4*)wsrc)[1];
      u16x8 wv;
      wv[0]=f2bf(wa.x); wv[1]=f2bf(wa.y); wv[2]=f2bf(wa.z); wv[3]=f2bf(wa.w);
      wv[4]=f2bf(wb.x); wv[5]=f2bf(wb.y); wv[6]=f2bf(wb.z); wv[7]=f2bf(wb.w);
      *(u16x8*)&sB[row * 32 + skc] = wv;
    }
    __syncthreads();

    u16x8 af[4], bfr[4];
#pragma unroll
    for (int mt = 0; mt < 4; ++mt)
      af[mt] = *(const u16x8*)&sA[(wm * 64 + mt * 16 + l15) * 32 + koff];
#pragma unroll
    for (int nt = 0; nt < 4; ++nt)
      bfr[nt] = *(const u16x8*)&sB[(wn * 64 + nt * 16 + l15) * 32 + koff];
#pragma unroll
    for (int mt = 0; mt < 4; ++mt)
#pragma unroll
      for (int nt = 0; nt < 4; ++nt)
        acc[mt][nt] = mfma16(af[mt], bfr[nt], acc[mt][nt]);
    __syncthreads();
  }

#pragma unroll
  for (int nt = 0; nt < 4; ++nt) {
    int colg = bn * 128 + wn * 64 + nt * 16 + l15;
    float bias = bih[colg] + bhh[colg];
#pragma unroll
    for (int mt = 0; mt < 4; ++mt) {
#pragma unroll
      for (int i = 0; i < 4; ++i) {
        int rowg = bm * 128 + wm * 64 + mt * 16 + (lane >> 4) * 4 + i;
        out[(size_t)rowg * HID + colg] = acc[mt][nt][i] + bias;
      }
    }
  }
}

// -------- fused 3-stage pipelined scan: 48 WGs --------
// stage 0 (WG 0..15):  h_l0[t] = tanh(xps[t] + h_l0[t-1]·W_hh0^T)           t = i
// stage 1 (WG 16..31): xps[t] <- h_l0[t]·W_ih1^T + b1   (overwrites slot t)  t = i-1
// stage 2 (WG 32..47): h_l1[t] = tanh(xps[t] + h_l1[t-1]·W_hh1^T) -> out    t = i-2
__global__ __launch_bounds__(256, 1)
void fused_scan(float* __restrict__ xps,
                const float* __restrict__ whh0,
                const float* __restrict__ wih1,
                const float* __restrict__ whh1,
                const float* __restrict__ bih1,
                const float* __restrict__ bhh1,
                unsigned short* __restrict__ h0b,
                float* __restrict__ out,
                unsigned int* __restrict__ ctr)
{
  const int tid  = threadIdx.x;
  const int lane = tid & 63;
  const int wave = tid >> 6;
  const int l15  = lane & 15;
  const int l4   = lane >> 4;
  const int stage = blockIdx.x >> 4;
  const int wg    = blockIdx.x & 15;
  const int col0  = wg * 64;
  const int kbase = wave * 256;
  const int frow  = tid >> 3;        // 0..31 batch row (finish phase)
  const int fcb   = (tid & 7) * 8;   // col offset within 64-col slice

  __shared__ float red[4][32][68];

  // persistent weight fragments (f32 -> bf16), 128 VGPRs
  const float* Wsl = (stage == 0) ? whh0 : (stage == 1) ? wih1 : whh1;
  u16x8 Bf[4][8];
#pragma unroll
  for (int nt = 0; nt < 4; ++nt) {
#pragma unroll
    for (int ks = 0; ks < 8; ++ks) {
      const float* src = Wsl + (size_t)(col0 + nt * 16 + l15) * HID + kbase + ks * 32 + l4 * 8;
      float4 a = ((const float4*)src)[0];
      float4 b = ((const float4*)src)[1];
      u16x8 v;
      v[0]=f2bf(a.x); v[1]=f2bf(a.y); v[2]=f2bf(a.z); v[3]=f2bf(a.w);
      v[4]=f2bf(b.x); v[5]=f2bf(b.y); v[6]=f2bf(b.z); v[7]=f2bf(b.w);
      Bf[nt][ks] = v;
    }
  }

  float biasv[8];
  if (stage == 1) {
#pragma unroll
    for (int j = 0; j < 8; ++j)
      biasv[j] = bih1[col0 + fcb + j] + bhh1[col0 + fcb + j];
  }

  // stage-0 xproj prefetch (atomic: L2-bypass, no allocation -> slot reusable by stage 1)
  unsigned long long xpv[4];
  if (stage == 0) {
    const float* np = xps + (size_t)frow * HID + col0 + fcb;
#pragma unroll
    for (int p = 0; p < 4; ++p) xpv[p] = ldat((const unsigned long long*)np + p);
  }

  for (int i = 0; i < SEQL + 2; ++i) {
    if (stage == 0 && i < SEQL) {
      const int t = i;
      f32x4 acc[2][4];
#pragma unroll
      for (int m = 0; m < 2; ++m)
#pragma unroll
        for (int n = 0; n < 4; ++n) acc[m][n] = (f32x4)0.f;
      if (t > 0) {
        const unsigned short* hp = h0b + (size_t)(t - 1) * (BSZ * HID);
        u16x8 Af[2][8];
#pragma unroll
        for (int m = 0; m < 2; ++m)
#pragma unroll
          for (int ks = 0; ks < 8; ++ks)
            Af[m][ks] = *(const u16x8*)(hp + (size_t)(m * 16 + l15) * HID + kbase + ks * 32 + l4 * 8);
#pragma unroll
        for (int ks = 0; ks < 8; ++ks)
#pragma unroll
          for (int m = 0; m < 2; ++m)
#pragma unroll
            for (int n = 0; n < 4; ++n)
              acc[m][n] = mfma16(Af[m][ks], Bf[n][ks], acc[m][n]);
      }
#pragma unroll
      for (int m = 0; m < 2; ++m)
#pragma unroll
        for (int n = 0; n < 4; ++n)
#pragma unroll
          for (int q = 0; q < 4; ++q)
            red[wave][m * 16 + l4 * 4 + q][n * 16 + l15] = acc[m][n][q];
      __syncthreads();
      float sv[8];
#pragma unroll
      for (int jj = 0; jj < 2; ++jj) {
        float4 r0 = *(const float4*)&red[0][frow][fcb + jj * 4];
        float4 r1 = *(const float4*)&red[1][frow][fcb + jj * 4];
        float4 r2 = *(const float4*)&red[2][frow][fcb + jj * 4];
        float4 r3 = *(const float4*)&red[3][frow][fcb + jj * 4];
        sv[jj*4+0] = r0.x + r1.x + r2.x + r3.x;
        sv[jj*4+1] = r0.y + r1.y + r2.y + r3.y;
        sv[jj*4+2] = r0.z + r1.z + r2.z + r3.z;
        sv[jj*4+3] = r0.w + r1.w + r2.w + r3.w;
      }
      float hv[8];
#pragma unroll
      for (int p = 0; p < 4; ++p) {
        float2 f = __builtin_bit_cast(float2, xpv[p]);
        hv[2*p]   = tanh_fast(sv[2*p]   + f.x);
        hv[2*p+1] = tanh_fast(sv[2*p+1] + f.y);
      }
      u16x8 hb;
#pragma unroll
      for (int j = 0; j < 8; ++j) hb[j] = f2bf(hv[j]);
      u64x2 hq = __builtin_bit_cast(u64x2, hb);
      unsigned long long* hdst =
          (unsigned long long*)(h0b + (size_t)t * (BSZ * HID) + (size_t)frow * HID + col0 + fcb);
      stwt(hdst, hq[0]); stwt(hdst + 1, hq[1]);
      if (t == SEQL - 1) {
        float* o = out + HN_OFF + (size_t)frow * HID + col0 + fcb;
        ((float4*)o)[0] = make_float4(hv[0], hv[1], hv[2], hv[3]);
        ((float4*)o)[1] = make_float4(hv[4], hv[5], hv[6], hv[7]);
      }
      if (t + 1 < SEQL) {
        const float* np = xps + ((size_t)(t + 1) * BSZ + frow) * HID + col0 + fcb;
#pragma unroll
        for (int p = 0; p < 4; ++p) xpv[p] = ldat((const unsigned long long*)np + p);
      }
    } else if (stage == 1 && i >= 1 && i <= SEQL) {
      const int t = i - 1;
      const unsigned short* hp = h0b + (size_t)t * (BSZ * HID);
      u16x8 Af[2][8];
#pragma unroll
      for (int m = 0; m < 2; ++m)
#pragma unroll
        for (int ks = 0; ks < 8; ++ks)
          Af[m][ks] = *(const u16x8*)(hp + (size_t)(m * 16 + l15) * HID + kbase + ks * 32 + l4 * 8);
      f32x4 acc[2][4];
#pragma unroll
      for (int m = 0; m < 2; ++m)
#pragma unroll
        for (int n = 0; n < 4; ++n) acc[m][n] = (f32x4)0.f;
#pragma unroll
      for (int ks = 0; ks < 8; ++ks)
#pragma unroll
        for (int m = 0; m < 2; ++m)
#pragma unroll
          for (int n = 0; n < 4; ++n)
            acc[m][n] = mfma16(Af[m][ks], Bf[n][ks], acc[m][n]);
#pragma unroll
      for (int m = 0; m < 2; ++m)
#pragma unroll
        for (int n = 0; n < 4; ++n)
#pragma unroll
          for (int q = 0; q < 4; ++q)
            red[wave][m * 16 + l4 * 4 + q][n * 16 + l15] = acc[m][n][q];
      __syncthreads();
      float sv[8];
#pragma unroll
      for (int jj = 0; jj < 2; ++jj) {
        float4 r0 = *(const float4*)&red[0][frow][fcb + jj * 4];
        float4 r1 = *(const float4*)&red[1][frow][fcb + jj * 4];
        float4 r2 = *(const float4*)&red[2][frow][fcb + jj * 4];
        float4 r3 = *(const float4*)&red[3][frow][fcb + jj * 4];
        sv[jj*4+0] = r0.x + r1.x + r2.x + r3.x;
        sv[jj*4+1] = r0.y + r1.y + r2.y + r3.y;
        sv[jj*4+2] = r0.z + r1.z + r2.z + r3.z;
        sv[jj*4+3] = r0.w + r1.w + r2.w + r3.w;
      }
      float* dst = xps + ((size_t)t * BSZ + frow) * HID + col0 + fcb;
#pragma unroll
      for (int p = 0; p < 4; ++p) {
        float2 f = make_float2(sv[2*p] + biasv[2*p], sv[2*p+1] + biasv[2*p+1]);
        stwt((unsigned long long*)dst + p, __builtin_bit_cast(unsigned long long, f));
      }
    } else if (stage == 2 && i >= 2) {
      const int t = i - 2;
      const float* qp = xps + ((size_t)t * BSZ + frow) * HID + col0 + fcb;
      float4 q0 = ((const float4*)qp)[0];
      float4 q1 = ((const float4*)qp)[1];
      f32x4 acc[2][4];
#pragma unroll
      for (int m = 0; m < 2; ++m)
#pragma unroll
        for (int n = 0; n < 4; ++n) acc[m][n] = (f32x4)0.f;
      if (t > 0) {
        u16x8 Af[2][8];
#pragma unroll
        for (int m = 0; m < 2; ++m)
#pragma unroll
          for (int ks = 0; ks < 8; ++ks) {
            const float* src = out + ((size_t)(m * 16 + l15) * SEQL + (t - 1)) * HID + kbase + ks * 32 + l4 * 8;
            float4 a = ((const float4*)src)[0];
            float4 b = ((const float4*)src)[1];
            bf16x8 bv;
            bv[0]=(__bf16)a.x; bv[1]=(__bf16)a.y; bv[2]=(__bf16)a.z; bv[3]=(__bf16)a.w;
            bv[4]=(__bf16)b.x; bv[5]=(__bf16)b.y; bv[6]=(__bf16)b.z; bv[7]=(__bf16)b.w;
            Af[m][ks] = __builtin_bit_cast(u16x8, bv);
          }
#pragma unroll
        for (int ks = 0; ks < 8; ++ks)
#pragma unroll
          for (int m = 0; m < 2; ++m)
#pragma unroll
            for (int n = 0; n < 4; ++n)
              acc[m][n] = mfma16(Af[m][ks], Bf[n][ks], acc[m][n]);
      }
#pragma unroll
      for (int m = 0; m < 2; ++m)
#pragma unroll
        for (int n = 0; n < 4; ++n)
#pragma unroll
          for (int q = 0; q < 4; ++q)
            red[wave][m * 16 + l4 * 4 + q][n * 16 + l15] = acc[m][n][q];
      __syncthreads();
      float sv[8];
#pragma unroll
      for (int jj = 0; jj < 2; ++jj) {
        float4 r0 = *(const float4*)&red[0][frow][fcb + jj * 4];
        float4 r1 = *(const float4*)&red[1][frow][fcb + jj * 4];
        float4 r2 = *(const float4*)&red[2][frow][fcb + jj * 4];
        float4 r3 = *(const float4*)&red[3][frow][fcb + jj * 4];
        sv[jj*4+0] = r0.x + r1.x + r2.x + r3.x;
        sv[jj*4+1] = r0.y + r1.y + r2.y + r3.y;
        sv[jj*4+2] = r0.z + r1.z + r2.z + r3.z;
        sv[jj*4+3] = r0.w + r1.w + r2.w + r3.w;
      }
      float xv[8] = {q0.x, q0.y, q0.z, q0.w, q1.x, q1.y, q1.z, q1.w};
      float hv[8];
#pragma unroll
      for (int j = 0; j < 8; ++j) hv[j] = tanh_fast(sv[j] + xv[j]);
      float* op = out + ((size_t)frow * SEQL + t) * HID + col0 + fcb;
#pragma unroll
      for (int p = 0; p < 4; ++p) {
        float2 f = make_float2(hv[2*p], hv[2*p+1]);
        stwt((unsigned long long*)op + p, __builtin_bit_cast(unsigned long long, f));
      }
      if (t == SEQL - 1) {
        float* o = out + HN_OFF + BSZ * HID + (size_t)frow * HID + col0 + fcb;
        ((float4*)o)[0] = make_float4(hv[0], hv[1], hv[2], hv[3]);
        ((float4*)o)[1] = make_float4(hv[4], hv[5], hv[6], hv[7]);
      }
    }
    if (i < SEQL + 1) arrive_wait(ctr, (unsigned)NWG * (i + 1));
  }
}

extern "C" void kernel_launch(void* const* d_in, const int* in_sizes, int n_in,
                              void* d_out, int out_size, void* d_ws, size_t ws_size,
                              hipStream_t stream) {
  const float* x    = (const float*)d_in[0];
  const float* w_ih = (const float*)d_in[1];
  const float* w_hh = (const float*)d_in[2];
  const float* b_ih = (const float*)d_in[3];
  const float* b_hh = (const float*)d_in[4];
  float* out = (float*)d_out;
  char* ws = (char*)d_ws;

  float* xps          = (float*)(ws + XPS_OFF);
  unsigned short* h0b = (unsigned short*)(ws + H0B_OFF);
  unsigned int* ctr   = (unsigned int*)(ws + CTR_OFF);

  init_kernel<<<1, 64, 0, stream>>>(ctr);
  xproj_gemm<<<1024, 256, 0, stream>>>(x, w_ih, b_ih, b_hh, xps);
  fused_scan<<<NWG, 256, 0, stream>>>(xps, w_hh,
      w_ih + (size_t)HID * HID, w_hh + (size_t)HID * HID,
      b_ih + HID, b_hh + HID, h0b, out, ctr);
}

// Round 3
// 4144.977 us; speedup vs baseline: 1.4228x; 1.1502x over previous
//
#include <hip/hip_runtime.h>

#define SEQL 512
#define BSZ  32
#define HID  1024
#define NWG  48
#define HN_OFF 16777216   // 32*512*1024

// ws layout (bytes): xps f32 [512][32][1024] @0 (64MB); h0b bf16 @64MB (32MB);
// flags @96MB: 3 sets x [512][16] u32 = 96KB
#define XPS_OFF 0u
#define H0B_OFF 67108864u
#define FLG_OFF 100663296u

using f32x4  = __attribute__((ext_vector_type(4))) float;
using u16x8  = __attribute__((ext_vector_type(8))) unsigned short;
using bf16x8 = __attribute__((ext_vector_type(8))) __bf16;
using u64x2  = __attribute__((ext_vector_type(2))) unsigned long long;

__device__ __forceinline__ f32x4 mfma16(u16x8 a, u16x8 b, f32x4 c) {
  return __builtin_amdgcn_mfma_f32_16x16x32_bf16(
      __builtin_bit_cast(bf16x8, a), __builtin_bit_cast(bf16x8, b), c, 0, 0, 0);
}

__device__ __forceinline__ unsigned short f2bf(float f) {
  unsigned u = __builtin_bit_cast(unsigned, f);
  u += 0x7fffu + ((u >> 16) & 1u);
  return (unsigned short)(u >> 16);
}

__device__ __forceinline__ float tanh_fast(float x) {
  float cx = fminf(fmaxf(x, -15.f), 15.f);
  float e = __expf(2.f * cx);
  return __fdividef(e - 1.f, e + 1.f);
}

// agent-scope write-through store / LLC-direct load (no L2 allocation)
__device__ __forceinline__ void stwt(unsigned long long* p, unsigned long long v) {
  __hip_atomic_store(p, v, __ATOMIC_RELAXED, __HIP_MEMORY_SCOPE_AGENT);
}
__device__ __forceinline__ unsigned long long ldat(const unsigned long long* p) {
  return __hip_atomic_load(p, __ATOMIC_RELAXED, __HIP_MEMORY_SCOPE_AGENT);
}
__device__ __forceinline__ unsigned ldat32(const unsigned* p) {
  return __hip_atomic_load(p, __ATOMIC_RELAXED, __HIP_MEMORY_SCOPE_AGENT);
}
__device__ __forceinline__ void stflag(unsigned* p) {
  __hip_atomic_store(p, 1u, __ATOMIC_RELAXED, __HIP_MEMORY_SCOPE_AGENT);
}

// wave waits for the 4 producer flags covering its K-slice: producers 4w..4w+3
__device__ __forceinline__ void wave_wait4(const unsigned* flt, int w, int lane) {
  const unsigned long long* q = (const unsigned long long*)flt + 2 * w + (lane & 1);
  unsigned long long v;
  do {
    v = ldat(q);
  } while (!__all(((unsigned)v != 0u) & ((unsigned)(v >> 32) != 0u)));
}
// wave waits on a single flag
__device__ __forceinline__ void wave_wait1(const unsigned* p) {
  while (!__all(ldat32(p) != 0u)) {}
}

__global__ void init_kernel(unsigned int* flg) {
  int i = blockIdx.x * 256 + threadIdx.x;   // 96*256 = 24576 = 3*512*16
  flg[i] = 0u;
}

// -------- xproj GEMM (layer 0): xps[s*32+b][h] = x[b][s][:]·W_ih0^T + b_ih0 + b_hh0
__global__ __launch_bounds__(256, 2)
void xproj_gemm(const float* __restrict__ X,
                const float* __restrict__ W,
                const float* __restrict__ bih,
                const float* __restrict__ bhh,
                float* __restrict__ out)
{
  __shared__ unsigned short sA[128 * 32];
  __shared__ unsigned short sB[128 * 32];
  const int tid  = threadIdx.x;
  const int lane = tid & 63;
  const int wave = tid >> 6;
  const int wm = wave >> 1, wn = wave & 1;
  const int bm = blockIdx.x >> 3;
  const int bn = blockIdx.x & 7;
  const int l15 = lane & 15;
  const int koff = (lane >> 4) * 8;
  const int srow = tid >> 2;
  const int skc  = (tid & 3) * 8;

  f32x4 acc[4][4];
#pragma unroll
  for (int i = 0; i < 4; ++i)
#pragma unroll
    for (int j = 0; j < 4; ++j) acc[i][j] = (f32x4)0.f;

  for (int k0 = 0; k0 < HID; k0 += 32) {
#pragma unroll
    for (int r = 0; r < 2; ++r) {
      int row = r * 64 + srow;
      int Mrow = bm * 128 + row;
      const float* src = X + ((size_t)(Mrow & 31) * SEQL + (Mrow >> 5)) * HID + k0 + skc;
      float4 a = ((const float4*)src)[0];
      float4 b = ((const float4*)src)[1];
      u16x8 av;
      av[0]=f2bf(a.x); av[1]=f2bf(a.y); av[2]=f2bf(a.z); av[3]=f2bf(a.w);
      av[4]=f2bf(b.x); av[5]=f2bf(b.y); av[6]=f2bf(b.z); av[7]=f2bf(b.w);
      *(u16x8*)&sA[row * 32 + skc] = av;

      const float* wsrc = W + (size_t)(bn * 128 + row) * HID + k0 + skc;
      float4 wa = ((const float4*)wsrc)[0];
      float4 wb = ((const float4*)wsrc)[1];
      u16x8 wv;
      wv[0]=f2bf(wa.x); wv[1]=f2bf(wa.y); wv[2]=f2bf(wa.z); wv[3]=f2bf(wa.w);
      wv[4]=f2bf(wb.x); wv[5]=f2bf(wb.y); wv[6]=f2bf(wb.z); wv[7]=f2bf(wb.w);
      *(u16x8*)&sB[row * 32 + skc] = wv;
    }
    __syncthreads();

    u16x8 af[4], bfr[4];
#pragma unroll
    for (int mt = 0; mt < 4; ++mt)
      af[mt] = *(const u16x8*)&sA[(wm * 64 + mt * 16 + l15) * 32 + koff];
#pragma unroll
    for (int nt = 0; nt < 4; ++nt)
      bfr[nt] = *(const u16x8*)&sB[(wn * 64 + nt * 16 + l15) * 32 + koff];
#pragma unroll
    for (int mt = 0; mt < 4; ++mt)
#pragma unroll
      for (int nt = 0; nt < 4; ++nt)
        acc[mt][nt] = mfma16(af[mt], bfr[nt], acc[mt][nt]);
    __syncthreads();
  }

#pragma unroll
  for (int nt = 0; nt < 4; ++nt) {
    int colg = bn * 128 + wn * 64 + nt * 16 + l15;
    float bias = bih[colg] + bhh[colg];
#pragma unroll
    for (int mt = 0; mt < 4; ++mt) {
#pragma unroll
      for (int i = 0; i < 4; ++i) {
        int rowg = bm * 128 + wm * 64 + mt * 16 + (lane >> 4) * 4 + i;
        out[(size_t)rowg * HID + colg] = acc[mt][nt][i] + bias;
      }
    }
  }
}

// -------- fused 3-stage DATAFLOW scan: 48 WGs, no global barrier --------
// stage 0 (WG 0..15):  h0[t] = tanh(xps[t] + h0[t-1]·W_hh0^T)         flag fl0[t][p]
// stage 1 (WG 16..31): xps[t] <- h0[t]·W_ih1^T + b1 (in place)        flag fl1[t][p]
// stage 2 (WG 32..47): h1[t] = tanh(xps[t] + h1[t-1]·W_hh1^T) -> out  flag fl2[t][p]
__global__ __launch_bounds__(256, 1)
void fused_scan(float* __restrict__ xps,
                const float* __restrict__ whh0,
                const float* __restrict__ wih1,
                const float* __restrict__ whh1,
                const float* __restrict__ bih1,
                const float* __restrict__ bhh1,
                unsigned short* __restrict__ h0b,
                float* __restrict__ out,
                unsigned int* __restrict__ flg)
{
  const int tid  = threadIdx.x;
  const int lane = tid & 63;
  const int wave = tid >> 6;
  const int l15  = lane & 15;
  const int l4   = lane >> 4;
  const int stage = blockIdx.x >> 4;
  const int wg    = blockIdx.x & 15;
  const int col0  = wg * 64;
  const int kbase = wave * 256;
  const int frow  = tid >> 3;        // 0..31 batch row (finish phase)
  const int fcb   = (tid & 7) * 8;   // col offset within 64-col slice

  unsigned* fl0 = flg;
  unsigned* fl1 = flg + SEQL * 16;
  unsigned* fl2 = flg + 2 * SEQL * 16;

  __shared__ float red[4][32][68];

  // persistent weight fragments (f32 -> bf16), 128 VGPRs
  const float* Wsl = (stage == 0) ? whh0 : (stage == 1) ? wih1 : whh1;
  u16x8 Bf[4][8];
#pragma unroll
  for (int nt = 0; nt < 4; ++nt) {
#pragma unroll
    for (int ks = 0; ks < 8; ++ks) {
      const float* src = Wsl + (size_t)(col0 + nt * 16 + l15) * HID + kbase + ks * 32 + l4 * 8;
      float4 a = ((const float4*)src)[0];
      float4 b = ((const float4*)src)[1];
      u16x8 v;
      v[0]=f2bf(a.x); v[1]=f2bf(a.y); v[2]=f2bf(a.z); v[3]=f2bf(a.w);
      v[4]=f2bf(b.x); v[5]=f2bf(b.y); v[6]=f2bf(b.z); v[7]=f2bf(b.w);
      Bf[nt][ks] = v;
    }
  }

  if (stage == 0) {
    // prefetch xproj for t=0 (LLC-direct: keeps xps out of L2, slot reusable by stage 1)
    unsigned long long xpv[4];
    {
      const float* np = xps + (size_t)frow * HID + col0 + fcb;
#pragma unroll
      for (int p = 0; p < 4; ++p) xpv[p] = ldat((const unsigned long long*)np + p);
    }
    for (int t = 0; t < SEQL; ++t) {
      f32x4 acc[2][4];
#pragma unroll
      for (int m = 0; m < 2; ++m)
#pragma unroll
        for (int n = 0; n < 4; ++n) acc[m][n] = (f32x4)0.f;
      if (t > 0) {
        wave_wait4(fl0 + (t - 1) * 16, wave, lane);
        const unsigned short* hp = h0b + (size_t)(t - 1) * (BSZ * HID);
        u16x8 Af[2][8];
#pragma unroll
        for (int m = 0; m < 2; ++m)
#pragma unroll
          for (int ks = 0; ks < 8; ++ks)
            Af[m][ks] = *(const u16x8*)(hp + (size_t)(m * 16 + l15) * HID + kbase + ks * 32 + l4 * 8);
#pragma unroll
        for (int ks = 0; ks < 8; ++ks)
#pragma unroll
          for (int m = 0; m < 2; ++m)
#pragma unroll
            for (int n = 0; n < 4; ++n)
              acc[m][n] = mfma16(Af[m][ks], Bf[n][ks], acc[m][n]);
      }
#pragma unroll
      for (int m = 0; m < 2; ++m)
#pragma unroll
        for (int n = 0; n < 4; ++n)
#pragma unroll
          for (int q = 0; q < 4; ++q)
            red[wave][m * 16 + l4 * 4 + q][n * 16 + l15] = acc[m][n][q];
      __syncthreads();
      float sv[8];
#pragma unroll
      for (int jj = 0; jj < 2; ++jj) {
        float4 r0 = *(const float4*)&red[0][frow][fcb + jj * 4];
        float4 r1 = *(const float4*)&red[1][frow][fcb + jj * 4];
        float4 r2 = *(const float4*)&red[2][frow][fcb + jj * 4];
        float4 r3 = *(const float4*)&red[3][frow][fcb + jj * 4];
        sv[jj*4+0] = r0.x + r1.x + r2.x + r3.x;
        sv[jj*4+1] = r0.y + r1.y + r2.y + r3.y;
        sv[jj*4+2] = r0.z + r1.z + r2.z + r3.z;
        sv[jj*4+3] = r0.w + r1.w + r2.w + r3.w;
      }
      float hv[8];
#pragma unroll
      for (int p = 0; p < 4; ++p) {
        float2 f = __builtin_bit_cast(float2, xpv[p]);
        hv[2*p]   = tanh_fast(sv[2*p]   + f.x);
        hv[2*p+1] = tanh_fast(sv[2*p+1] + f.y);
      }
      u16x8 hb;
#pragma unroll
      for (int j = 0; j < 8; ++j) hb[j] = f2bf(hv[j]);
      u64x2 hq = __builtin_bit_cast(u64x2, hb);
      unsigned long long* hdst =
          (unsigned long long*)(h0b + (size_t)t * (BSZ * HID) + (size_t)frow * HID + col0 + fcb);
      stwt(hdst, hq[0]); stwt(hdst + 1, hq[1]);
      if (t == SEQL - 1) {
        float* o = out + HN_OFF + (size_t)frow * HID + col0 + fcb;
        ((float4*)o)[0] = make_float4(hv[0], hv[1], hv[2], hv[3]);
        ((float4*)o)[1] = make_float4(hv[4], hv[5], hv[6], hv[7]);
      } else {
        const float* np = xps + ((size_t)(t + 1) * BSZ + frow) * HID + col0 + fcb;
#pragma unroll
        for (int p = 0; p < 4; ++p) xpv[p] = ldat((const unsigned long long*)np + p);
      }
      asm volatile("s_waitcnt vmcnt(0)" ::: "memory");
      __syncthreads();
      if (tid == 0) stflag(&fl0[t * 16 + wg]);
    }
  } else if (stage == 1) {
    for (int t = 0; t < SEQL; ++t) {
      wave_wait4(fl0 + t * 16, wave, lane);
      const unsigned short* hp = h0b + (size_t)t * (BSZ * HID);
      u16x8 Af[2][8];
#pragma unroll
      for (int m = 0; m < 2; ++m)
#pragma unroll
        for (int ks = 0; ks < 8; ++ks)
          Af[m][ks] = *(const u16x8*)(hp + (size_t)(m * 16 + l15) * HID + kbase + ks * 32 + l4 * 8);
      f32x4 acc[2][4];
#pragma unroll
      for (int m = 0; m < 2; ++m)
#pragma unroll
        for (int n = 0; n < 4; ++n) acc[m][n] = (f32x4)0.f;
#pragma unroll
      for (int ks = 0; ks < 8; ++ks)
#pragma unroll
        for (int m = 0; m < 2; ++m)
#pragma unroll
          for (int n = 0; n < 4; ++n)
            acc[m][n] = mfma16(Af[m][ks], Bf[n][ks], acc[m][n]);
#pragma unroll
      for (int m = 0; m < 2; ++m)
#pragma unroll
        for (int n = 0; n < 4; ++n)
#pragma unroll
          for (int q = 0; q < 4; ++q)
            red[wave][m * 16 + l4 * 4 + q][n * 16 + l15] = acc[m][n][q];
      __syncthreads();
      float sv[8];
#pragma unroll
      for (int jj = 0; jj < 2; ++jj) {
        float4 r0 = *(const float4*)&red[0][frow][fcb + jj * 4];
        float4 r1 = *(const float4*)&red[1][frow][fcb + jj * 4];
        float4 r2 = *(const float4*)&red[2][frow][fcb + jj * 4];
        float4 r3 = *(const float4*)&red[3][frow][fcb + jj * 4];
        sv[jj*4+0] = r0.x + r1.x + r2.x + r3.x;
        sv[jj*4+1] = r0.y + r1.y + r2.y + r3.y;
        sv[jj*4+2] = r0.z + r1.z + r2.z + r3.z;
        sv[jj*4+3] = r0.w + r1.w + r2.w + r3.w;
      }
      float bia[8];
#pragma unroll
      for (int j = 0; j < 8; ++j)
        bia[j] = bih1[col0 + fcb + j] + bhh1[col0 + fcb + j];
      float* dst = xps + ((size_t)t * BSZ + frow) * HID + col0 + fcb;
#pragma unroll
      for (int p = 0; p < 4; ++p) {
        float2 f = make_float2(sv[2*p] + bia[2*p], sv[2*p+1] + bia[2*p+1]);
        stwt((unsigned long long*)dst + p, __builtin_bit_cast(unsigned long long, f));
      }
      asm volatile("s_waitcnt vmcnt(0)" ::: "memory");
      __syncthreads();
      if (tid == 0) stflag(&fl1[t * 16 + wg]);
    }
  } else {
    for (int t = 0; t < SEQL; ++t) {
      f32x4 acc[2][4];
#pragma unroll
      for (int m = 0; m < 2; ++m)
#pragma unroll
        for (int n = 0; n < 4; ++n) acc[m][n] = (f32x4)0.f;
      if (t > 0) {
        wave_wait4(fl2 + (t - 1) * 16, wave, lane);
        u16x8 Af[2][8];
#pragma unroll
        for (int m = 0; m < 2; ++m)
#pragma unroll
          for (int ks = 0; ks < 8; ++ks) {
            const float* src = out + ((size_t)(m * 16 + l15) * SEQL + (t - 1)) * HID + kbase + ks * 32 + l4 * 8;
            float4 a = ((const float4*)src)[0];
            float4 b = ((const float4*)src)[1];
            bf16x8 bv;
            bv[0]=(__bf16)a.x; bv[1]=(__bf16)a.y; bv[2]=(__bf16)a.z; bv[3]=(__bf16)a.w;
            bv[4]=(__bf16)b.x; bv[5]=(__bf16)b.y; bv[6]=(__bf16)b.z; bv[7]=(__bf16)b.w;
            Af[m][ks] = __builtin_bit_cast(u16x8, bv);
          }
#pragma unroll
        for (int ks = 0; ks < 8; ++ks)
#pragma unroll
          for (int m = 0; m < 2; ++m)
#pragma unroll
            for (int n = 0; n < 4; ++n)
              acc[m][n] = mfma16(Af[m][ks], Bf[n][ks], acc[m][n]);
      }
#pragma unroll
      for (int m = 0; m < 2; ++m)
#pragma unroll
        for (int n = 0; n < 4; ++n)
#pragma unroll
          for (int q = 0; q < 4; ++q)
            red[wave][m * 16 + l4 * 4 + q][n * 16 + l15] = acc[m][n][q];
      __syncthreads();
      // wait for my xproj1 slice (point-to-point: stage-1 WG with same index)
      wave_wait1(&fl1[t * 16 + wg]);
      const float* qp = xps + ((size_t)t * BSZ + frow) * HID + col0 + fcb;
      float4 q0 = ((const float4*)qp)[0];
      float4 q1 = ((const float4*)qp)[1];
      float sv[8];
#pragma unroll
      for (int jj = 0; jj < 2; ++jj) {
        float4 r0 = *(const float4*)&red[0][frow][fcb + jj * 4];
        float4 r1 = *(const float4*)&red[1][frow][fcb + jj * 4];
        float4 r2 = *(const float4*)&red[2][frow][fcb + jj * 4];
        float4 r3 = *(const float4*)&red[3][frow][fcb + jj * 4];
        sv[jj*4+0] = r0.x + r1.x + r2.x + r3.x;
        sv[jj*4+1] = r0.y + r1.y + r2.y + r3.y;
        sv[jj*4+2] = r0.z + r1.z + r2.z + r3.z;
        sv[jj*4+3] = r0.w + r1.w + r2.w + r3.w;
      }
      float xv[8] = {q0.x, q0.y, q0.z, q0.w, q1.x, q1.y, q1.z, q1.w};
      float hv[8];
#pragma unroll
      for (int j = 0; j < 8; ++j) hv[j] = tanh_fast(sv[j] + xv[j]);
      float* op = out + ((size_t)frow * SEQL + t) * HID + col0 + fcb;
#pragma unroll
      for (int p = 0; p < 4; ++p) {
        float2 f = make_float2(hv[2*p], hv[2*p+1]);
        stwt((unsigned long long*)op + p, __builtin_bit_cast(unsigned long long, f));
      }
      if (t == SEQL - 1) {
        float* o = out + HN_OFF + BSZ * HID + (size_t)frow * HID + col0 + fcb;
        ((float4*)o)[0] = make_float4(hv[0], hv[1], hv[2], hv[3]);
        ((float4*)o)[1] = make_float4(hv[4], hv[5], hv[6], hv[7]);
      }
      asm volatile("s_waitcnt vmcnt(0)" ::: "memory");
      __syncthreads();
      if (tid == 0) stflag(&fl2[t * 16 + wg]);
    }
  }
}

extern "C" void kernel_launch(void* const* d_in, const int* in_sizes, int n_in,
                              void* d_out, int out_size, void* d_ws, size_t ws_size,
                              hipStream_t stream) {
  const float* x    = (const float*)d_in[0];
  const float* w_ih = (const float*)d_in[1];
  const float* w_hh = (const float*)d_in[2];
  const float* b_ih = (const float*)d_in[3];
  const float* b_hh = (const float*)d_in[4];
  float* out = (float*)d_out;
  char* ws = (char*)d_ws;

  float* xps          = (float*)(ws + XPS_OFF);
  unsigned short* h0b = (unsigned short*)(ws + H0B_OFF);
  unsigned int* flg   = (unsigned int*)(ws + FLG_OFF);

  init_kernel<<<96, 256, 0, stream>>>(flg);
  xproj_gemm<<<1024, 256, 0, stream>>>(x, w_ih, b_ih, b_hh, xps);
  fused_scan<<<NWG, 256, 0, stream>>>(xps, w_hh,
      w_ih + (size_t)HID * HID, w_hh + (size_t)HID * HID,
      b_ih + HID, b_hh + HID, h0b, out, flg);
}

// Round 5
// 3787.627 us; speedup vs baseline: 1.5571x; 1.0943x over previous
//
#include <hip/hip_runtime.h>

#define SEQL 512
#define BSZ  32
#define HID  1024
#define NWORK 48
#define NLAUNCH 384
#define HN_OFF 16777216   // 32*512*1024

// ws layout (bytes): xps f16 [512][32][1024] @0 (32MB, overwritten in place with xp1);
// h0b bf16 @32MB (32MB); h1b bf16 @64MB (32MB); flags @96MB (3*512*16 u32 = 96KB);
// boot @96MB+128KB (17 ints). Total < 96.2MB.
#define XPS_OFF 0u
#define H0B_OFF 33554432u
#define H1B_OFF 67108864u
#define FLG_OFF 100663296u
#define BOOT_OFF 100794368u

using f32x4  = __attribute__((ext_vector_type(4))) float;
using u16x8  = __attribute__((ext_vector_type(8))) unsigned short;
using u32x4  = __attribute__((ext_vector_type(4))) unsigned int;
using bf16x8 = __attribute__((ext_vector_type(8))) __bf16;

__device__ __forceinline__ f32x4 mfma16(u16x8 a, u16x8 b, f32x4 c) {
  return __builtin_amdgcn_mfma_f32_16x16x32_bf16(
      __builtin_bit_cast(bf16x8, a), __builtin_bit_cast(bf16x8, b), c, 0, 0, 0);
}

__device__ __forceinline__ unsigned short f2bf(float f) {
  unsigned u = __builtin_bit_cast(unsigned, f);
  u += 0x7fffu + ((u >> 16) & 1u);
  return (unsigned short)(u >> 16);
}
__device__ __forceinline__ unsigned short f2h(float f) {
  _Float16 h = (_Float16)f;
  return __builtin_bit_cast(unsigned short, h);
}
__device__ __forceinline__ float h2f(unsigned short u) {
  return (float)__builtin_bit_cast(_Float16, u);
}

__device__ __forceinline__ float tanh_fast(float x) {
  float cx = fminf(fmaxf(x, -15.f), 15.f);
  float e = __expf(2.f * cx);
  return __fdividef(e - 1.f, e + 1.f);
}

// ---- sc0 (L1-bypass, L2-served) batched tile load: bf16 [32][1024] K-slice,
// rows l15 & l15+16, chunks ks*64B. base = tile + l15*HID + kbase + l4*8 (elems).
__device__ __forceinline__ void ld_tile_sc0(const unsigned short* base, u32x4 (&r)[16]) {
  const char* b0 = (const char*)base;
  const char* b1 = b0 + 16 * HID * 2;
  asm volatile(
    "global_load_dwordx4 %0, %16, off sc0\n\t"
    "global_load_dwordx4 %1, %16, off offset:64 sc0\n\t"
    "global_load_dwordx4 %2, %16, off offset:128 sc0\n\t"
    "global_load_dwordx4 %3, %16, off offset:192 sc0\n\t"
    "global_load_dwordx4 %4, %16, off offset:256 sc0\n\t"
    "global_load_dwordx4 %5, %16, off offset:320 sc0\n\t"
    "global_load_dwordx4 %6, %16, off offset:384 sc0\n\t"
    "global_load_dwordx4 %7, %16, off offset:448 sc0\n\t"
    "global_load_dwordx4 %8, %17, off sc0\n\t"
    "global_load_dwordx4 %9, %17, off offset:64 sc0\n\t"
    "global_load_dwordx4 %10, %17, off offset:128 sc0\n\t"
    "global_load_dwordx4 %11, %17, off offset:192 sc0\n\t"
    "global_load_dwordx4 %12, %17, off offset:256 sc0\n\t"
    "global_load_dwordx4 %13, %17, off offset:320 sc0\n\t"
    "global_load_dwordx4 %14, %17, off offset:384 sc0\n\t"
    "global_load_dwordx4 %15, %17, off offset:448 sc0\n\t"
    "s_waitcnt vmcnt(0)"
    : "=&v"(r[0]), "=&v"(r[1]), "=&v"(r[2]), "=&v"(r[3]),
      "=&v"(r[4]), "=&v"(r[5]), "=&v"(r[6]), "=&v"(r[7]),
      "=&v"(r[8]), "=&v"(r[9]), "=&v"(r[10]), "=&v"(r[11]),
      "=&v"(r[12]), "=&v"(r[13]), "=&v"(r[14]), "=&v"(r[15])
    : "v"(b0), "v"(b1)
    : "memory");
}

// 16B sc0 load (8 f16/bf16 elements)
__device__ __forceinline__ u16x8 ld8h_sc0(const void* p) {
  u32x4 r;
  asm volatile("global_load_dwordx4 %0, %1, off sc0\n\ts_waitcnt vmcnt(0)"
               : "=&v"(r) : "v"(p) : "memory");
  return __builtin_bit_cast(u16x8, r);
}

// ---- flags: agent-scope atomics (proven correct in rounds 2-3)
__device__ __forceinline__ void flag_set(unsigned* p) {
  __hip_atomic_store(p, 1u, __ATOMIC_RELAXED, __HIP_MEMORY_SCOPE_AGENT);
}
__device__ __forceinline__ unsigned flag_get(const unsigned* p) {
  return __hip_atomic_load(p, __ATOMIC_RELAXED, __HIP_MEMORY_SCOPE_AGENT);
}
// wave waits for the 4 producer flags covering its K-slice (producers 4w..4w+3)
__device__ __forceinline__ void wave_wait4(const unsigned* flt, int wave, int lane) {
  const unsigned* p = flt + wave * 4 + (lane & 3);
  while (!__all(flag_get(p) != 0u)) {}
}
__device__ __forceinline__ void wave_wait1(const unsigned* p) {
  while (!__all(flag_get(p) != 0u)) {}
}

__global__ void init_kernel(unsigned* flg, int* boot) {
  int i = blockIdx.x * 256 + threadIdx.x;   // 96*256 = 24576 = 3*512*16
  flg[i] = 0u;
  if (blockIdx.x == 0) {
    if (threadIdx.x < 16) boot[threadIdx.x] = 0;
    if (threadIdx.x == 16) boot[16] = -1;
  }
}

// -------- xproj GEMM (layer 0): xps[s*32+b][h] = x[b][s][:]·W_ih0^T + b_ih0 + b_hh0 (f16 out)
__global__ __launch_bounds__(256, 2)
void xproj_gemm(const float* __restrict__ X,
                const float* __restrict__ W,
                const float* __restrict__ bih,
                const float* __restrict__ bhh,
                unsigned short* __restrict__ out)
{
  __shared__ unsigned short sA[128 * 32];
  __shared__ unsigned short sB[128 * 32];
  const int tid  = threadIdx.x;
  const int lane = tid & 63;
  const int wave = tid >> 6;
  const int wm = wave >> 1, wn = wave & 1;
  const int bm = blockIdx.x >> 3;
  const int bn = blockIdx.x & 7;
  const int l15 = lane & 15;
  const int koff = (lane >> 4) * 8;
  const int srow = tid >> 2;
  const int skc  = (tid & 3) * 8;

  f32x4 acc[4][4];
#pragma unroll
  for (int i = 0; i < 4; ++i)
#pragma unroll
    for (int j = 0; j < 4; ++j) acc[i][j] = (f32x4)0.f;

  for (int k0 = 0; k0 < HID; k0 += 32) {
#pragma unroll
    for (int r = 0; r < 2; ++r) {
      int row = r * 64 + srow;
      int Mrow = bm * 128 + row;
      const float* src = X + ((size_t)(Mrow & 31) * SEQL + (Mrow >> 5)) * HID + k0 + skc;
      float4 a = ((const float4*)src)[0];
      float4 b = ((const float4*)src)[1];
      u16x8 av;
      av[0]=f2bf(a.x); av[1]=f2bf(a.y); av[2]=f2bf(a.z); av[3]=f2bf(a.w);
      av[4]=f2bf(b.x); av[5]=f2bf(b.y); av[6]=f2bf(b.z); av[7]=f2bf(b.w);
      *(u16x8*)&sA[row * 32 + skc] = av;

      const float* wsrc = W + (size_t)(bn * 128 + row) * HID + k0 + skc;
      float4 wa = ((const float4*)wsrc)[0];
      float4 wb = ((const float4*)wsrc)[1];
      u16x8 wv;
      wv[0]=f2bf(wa.x); wv[1]=f2bf(wa.y); wv[2]=f2bf(wa.z); wv[3]=f2bf(wa.w);
      wv[4]=f2bf(wb.x); wv[5]=f2bf(wb.y); wv[6]=f2bf(wb.z); wv[7]=f2bf(wb.w);
      *(u16x8*)&sB[row * 32 + skc] = wv;
    }
    __syncthreads();

    u16x8 af[4], bfr[4];
#pragma unroll
    for (int mt = 0; mt < 4; ++mt)
      af[mt] = *(const u16x8*)&sA[(wm * 64 + mt * 16 + l15) * 32 + koff];
#pragma unroll
    for (int nt = 0; nt < 4; ++nt)
      bfr[nt] = *(const u16x8*)&sB[(wn * 64 + nt * 16 + l15) * 32 + koff];
#pragma unroll
    for (int mt = 0; mt < 4; ++mt)
#pragma unroll
      for (int nt = 0; nt < 4; ++nt)
        acc[mt][nt] = mfma16(af[mt], bfr[nt], acc[mt][nt]);
    __syncthreads();
  }

#pragma unroll
  for (int nt = 0; nt < 4; ++nt) {
    int colg = bn * 128 + wn * 64 + nt * 16 + l15;
    float bias = bih[colg] + bhh[colg];
#pragma unroll
    for (int mt = 0; mt < 4; ++mt) {
#pragma unroll
      for (int i = 0; i < 4; ++i) {
        int rowg = bm * 128 + wm * 64 + mt * 16 + (lane >> 4) * 4 + i;
        out[(size_t)rowg * HID + colg] = f2h(acc[mt][nt][i] + bias);
      }
    }
  }
}

// -------- fused 3-stage scan, all workers colocated on ONE XCD --------
// S0 (role 0..15):  h0[t] = tanh(xps[t] + h0[t-1]·W_hh0^T) -> h0b, flag flA
// S1 (role 16..31): xp1[t] = h0[t]·W_ih1^T + b1 -> xps[t] slot (f16), flag flB
// S2 (role 32..47): h1[t] = tanh(xp1[t] + h1[t-1]·W_hh1^T) -> h1b + out, flag flC
__global__ __launch_bounds__(256, 2)
void fused_scan(unsigned short* __restrict__ xps,   // f16 [512][32][1024], in-place xp1
                const float* __restrict__ whh0,
                const float* __restrict__ wih1,
                const float* __restrict__ whh1,
                const float* __restrict__ bih1,
                const float* __restrict__ bhh1,
                unsigned short* __restrict__ h0b,
                unsigned short* __restrict__ h1b,
                float* __restrict__ out,
                unsigned* __restrict__ flg,
                int* __restrict__ boot)
{
  const int tid  = threadIdx.x;

  // ---- XCD-colocation bootstrap ----
  __shared__ int s_role;
  if (tid == 0) {
    unsigned xcc;
    asm volatile("s_getreg_b32 %0, hwreg(HW_REG_XCC_ID)" : "=s"(xcc));
    xcc &= 15u;
    int slot = __hip_atomic_fetch_add(&boot[(int)xcc], 1, __ATOMIC_RELAXED,
                                      __HIP_MEMORY_SCOPE_AGENT);
    if (slot == NWORK - 1) {
      int exp = -1;
      __hip_atomic_compare_exchange_strong(&boot[16], &exp, (int)xcc,
          __ATOMIC_RELAXED, __ATOMIC_RELAXED, __HIP_MEMORY_SCOPE_AGENT);
    }
    int ch;
    while ((ch = __hip_atomic_load(&boot[16], __ATOMIC_RELAXED,
                                   __HIP_MEMORY_SCOPE_AGENT)) < 0)
      __builtin_amdgcn_s_sleep(8);
    s_role = ((int)xcc == ch && slot < NWORK) ? slot : -1;
  }
  __syncthreads();
  const int role = s_role;
  if (role < 0) return;

  const int lane = tid & 63;
  const int wave = tid >> 6;
  const int l15  = lane & 15;
  const int l4   = lane >> 4;
  const int stage = role >> 4;
  const int wg    = role & 15;
  const int col0  = wg * 64;
  const int kbase = wave * 256;
  const int frow  = tid >> 3;        // 0..31 batch row (finish phase)
  const int fcb   = (tid & 7) * 8;   // col offset within 64-col slice
  const int laneoff = l15 * HID + kbase + l4 * 8;

  unsigned* flA = flg;
  unsigned* flB = flg + SEQL * 16;
  unsigned* flC = flg + 2 * SEQL * 16;

  __shared__ float red[4][32][68];

  // persistent weight fragments (f32 -> bf16), 128 VGPRs
  const float* Wsl = (stage == 0) ? whh0 : (stage == 1) ? wih1 : whh1;
  u16x8 Bf[4][8];
#pragma unroll
  for (int nt = 0; nt < 4; ++nt)
#pragma unroll
    for (int ks = 0; ks < 8; ++ks) {
      const float* src = Wsl + (size_t)(col0 + nt * 16 + l15) * HID + kbase + ks * 32 + l4 * 8;
      float4 a = ((const float4*)src)[0];
      float4 b = ((const float4*)src)[1];
      u16x8 v;
      v[0]=f2bf(a.x); v[1]=f2bf(a.y); v[2]=f2bf(a.z); v[3]=f2bf(a.w);
      v[4]=f2bf(b.x); v[5]=f2bf(b.y); v[6]=f2bf(b.z); v[7]=f2bf(b.w);
      Bf[nt][ks] = v;
    }

  if (stage == 0) {
    // prefetch xps[0] (plain cached load — read-only v1 data)
    u16x8 xh = *(const u16x8*)(xps + (size_t)frow * HID + col0 + fcb);
    for (int t = 0; t < SEQL; ++t) {
      f32x4 acc[2][4];
#pragma unroll
      for (int m = 0; m < 2; ++m)
#pragma unroll
        for (int n = 0; n < 4; ++n) acc[m][n] = (f32x4)0.f;
      if (t > 0) {
        wave_wait4(flA + (t - 1) * 16, wave, lane);
        u32x4 r[16];
        ld_tile_sc0(h0b + (size_t)(t - 1) * (BSZ * HID) + laneoff, r);
#pragma unroll
        for (int ks = 0; ks < 8; ++ks)
#pragma unroll
          for (int m = 0; m < 2; ++m)
#pragma unroll
            for (int n = 0; n < 4; ++n)
              acc[m][n] = mfma16(__builtin_bit_cast(u16x8, r[m * 8 + ks]), Bf[n][ks], acc[m][n]);
      }
#pragma unroll
      for (int m = 0; m < 2; ++m)
#pragma unroll
        for (int n = 0; n < 4; ++n)
#pragma unroll
          for (int q = 0; q < 4; ++q)
            red[wave][m * 16 + l4 * 4 + q][n * 16 + l15] = acc[m][n][q];
      __syncthreads();
      float hv[8];
#pragma unroll
      for (int jj = 0; jj < 2; ++jj) {
        float4 r0 = *(const float4*)&red[0][frow][fcb + jj * 4];
        float4 r1 = *(const float4*)&red[1][frow][fcb + jj * 4];
        float4 r2 = *(const float4*)&red[2][frow][fcb + jj * 4];
        float4 r3 = *(const float4*)&red[3][frow][fcb + jj * 4];
        hv[jj*4+0] = r0.x + r1.x + r2.x + r3.x;
        hv[jj*4+1] = r0.y + r1.y + r2.y + r3.y;
        hv[jj*4+2] = r0.z + r1.z + r2.z + r3.z;
        hv[jj*4+3] = r0.w + r1.w + r2.w + r3.w;
      }
#pragma unroll
      for (int j = 0; j < 8; ++j) hv[j] = tanh_fast(hv[j] + h2f((unsigned short)xh[j]));
      u16x8 hb;
#pragma unroll
      for (int j = 0; j < 8; ++j) hb[j] = f2bf(hv[j]);
      *(u16x8*)(h0b + (size_t)t * (BSZ * HID) + (size_t)frow * HID + col0 + fcb) = hb;
      if (t == SEQL - 1) {
        float* o = out + HN_OFF + (size_t)frow * HID + col0 + fcb;
        ((float4*)o)[0] = make_float4(hv[0], hv[1], hv[2], hv[3]);
        ((float4*)o)[1] = make_float4(hv[4], hv[5], hv[6], hv[7]);
      } else {
        xh = *(const u16x8*)(xps + ((size_t)(t + 1) * BSZ + frow) * HID + col0 + fcb);
      }
      asm volatile("s_waitcnt vmcnt(0)" ::: "memory");   // stores at L2 (coherence pt)
      __syncthreads();
      if (tid == 0) flag_set(&flA[t * 16 + wg]);
    }
  } else if (stage == 1) {
    float bia[8];
#pragma unroll
    for (int j = 0; j < 8; ++j)
      bia[j] = bih1[col0 + fcb + j] + bhh1[col0 + fcb + j];
    for (int t = 0; t < SEQL; ++t) {
      wave_wait4(flA + t * 16, wave, lane);
      u32x4 r[16];
      ld_tile_sc0(h0b + (size_t)t * (BSZ * HID) + laneoff, r);
      f32x4 acc[2][4];
#pragma unroll
      for (int m = 0; m < 2; ++m)
#pragma unroll
        for (int n = 0; n < 4; ++n) acc[m][n] = (f32x4)0.f;
#pragma unroll
      for (int ks = 0; ks < 8; ++ks)
#pragma unroll
        for (int m = 0; m < 2; ++m)
#pragma unroll
          for (int n = 0; n < 4; ++n)
            acc[m][n] = mfma16(__builtin_bit_cast(u16x8, r[m * 8 + ks]), Bf[n][ks], acc[m][n]);
#pragma unroll
      for (int m = 0; m < 2; ++m)
#pragma unroll
        for (int n = 0; n < 4; ++n)
#pragma unroll
          for (int q = 0; q < 4; ++q)
            red[wave][m * 16 + l4 * 4 + q][n * 16 + l15] = acc[m][n][q];
      __syncthreads();
      float sv[8];
#pragma unroll
      for (int jj = 0; jj < 2; ++jj) {
        float4 r0 = *(const float4*)&red[0][frow][fcb + jj * 4];
        float4 r1 = *(const float4*)&red[1][frow][fcb + jj * 4];
        float4 r2 = *(const float4*)&red[2][frow][fcb + jj * 4];
        float4 r3 = *(const float4*)&red[3][frow][fcb + jj * 4];
        sv[jj*4+0] = r0.x + r1.x + r2.x + r3.x;
        sv[jj*4+1] = r0.y + r1.y + r2.y + r3.y;
        sv[jj*4+2] = r0.z + r1.z + r2.z + r3.z;
        sv[jj*4+3] = r0.w + r1.w + r2.w + r3.w;
      }
      u16x8 xo;
#pragma unroll
      for (int j = 0; j < 8; ++j) xo[j] = f2h(sv[j] + bia[j]);
      *(u16x8*)(xps + ((size_t)t * BSZ + frow) * HID + col0 + fcb) = xo;
      asm volatile("s_waitcnt vmcnt(0)" ::: "memory");
      __syncthreads();
      if (tid == 0) flag_set(&flB[t * 16 + wg]);
    }
  } else {
    for (int t = 0; t < SEQL; ++t) {
      f32x4 acc[2][4];
#pragma unroll
      for (int m = 0; m < 2; ++m)
#pragma unroll
        for (int n = 0; n < 4; ++n) acc[m][n] = (f32x4)0.f;
      if (t > 0) {
        wave_wait4(flC + (t - 1) * 16, wave, lane);
        u32x4 r[16];
        ld_tile_sc0(h1b + (size_t)(t - 1) * (BSZ * HID) + laneoff, r);
#pragma unroll
        for (int ks = 0; ks < 8; ++ks)
#pragma unroll
          for (int m = 0; m < 2; ++m)
#pragma unroll
            for (int n = 0; n < 4; ++n)
              acc[m][n] = mfma16(__builtin_bit_cast(u16x8, r[m * 8 + ks]), Bf[n][ks], acc[m][n]);
      }
#pragma unroll
      for (int m = 0; m < 2; ++m)
#pragma unroll
        for (int n = 0; n < 4; ++n)
#pragma unroll
          for (int q = 0; q < 4; ++q)
            red[wave][m * 16 + l4 * 4 + q][n * 16 + l15] = acc[m][n][q];
      __syncthreads();
      // my xp1 slice (f16, written in place by S1 WG wg) — sc0 mandatory (v2 of line)
      wave_wait1(&flB[t * 16 + wg]);
      u16x8 xq = ld8h_sc0(xps + ((size_t)t * BSZ + frow) * HID + col0 + fcb);
      float hv[8];
#pragma unroll
      for (int jj = 0; jj < 2; ++jj) {
        float4 r0 = *(const float4*)&red[0][frow][fcb + jj * 4];
        float4 r1 = *(const float4*)&red[1][frow][fcb + jj * 4];
        float4 r2 = *(const float4*)&red[2][frow][fcb + jj * 4];
        float4 r3 = *(const float4*)&red[3][frow][fcb + jj * 4];
        hv[jj*4+0] = r0.x + r1.x + r2.x + r3.x;
        hv[jj*4+1] = r0.y + r1.y + r2.y + r3.y;
        hv[jj*4+2] = r0.z + r1.z + r2.z + r3.z;
        hv[jj*4+3] = r0.w + r1.w + r2.w + r3.w;
      }
#pragma unroll
      for (int j = 0; j < 8; ++j) hv[j] = tanh_fast(hv[j] + h2f((unsigned short)xq[j]));
      u16x8 hb;
#pragma unroll
      for (int j = 0; j < 8; ++j) hb[j] = f2bf(hv[j]);
      *(u16x8*)(h1b + (size_t)t * (BSZ * HID) + (size_t)frow * HID + col0 + fcb) = hb;
      float* op = out + ((size_t)frow * SEQL + t) * HID + col0 + fcb;
      ((float4*)op)[0] = make_float4(hv[0], hv[1], hv[2], hv[3]);
      ((float4*)op)[1] = make_float4(hv[4], hv[5], hv[6], hv[7]);
      if (t == SEQL - 1) {
        float* o = out + HN_OFF + BSZ * HID + (size_t)frow * HID + col0 + fcb;
        ((float4*)o)[0] = make_float4(hv[0], hv[1], hv[2], hv[3]);
        ((float4*)o)[1] = make_float4(hv[4], hv[5], hv[6], hv[7]);
      }
      asm volatile("s_waitcnt vmcnt(0)" ::: "memory");
      __syncthreads();
      if (tid == 0) flag_set(&flC[t * 16 + wg]);
    }
  }
}

extern "C" void kernel_launch(void* const* d_in, const int* in_sizes, int n_in,
                              void* d_out, int out_size, void* d_ws, size_t ws_size,
                              hipStream_t stream) {
  const float* x    = (const float*)d_in[0];
  const float* w_ih = (const float*)d_in[1];
  const float* w_hh = (const float*)d_in[2];
  const float* b_ih = (const float*)d_in[3];
  const float* b_hh = (const float*)d_in[4];
  float* out = (float*)d_out;
  char* ws = (char*)d_ws;

  unsigned short* xps = (unsigned short*)(ws + XPS_OFF);
  unsigned short* h0b = (unsigned short*)(ws + H0B_OFF);
  unsigned short* h1b = (unsigned short*)(ws + H1B_OFF);
  unsigned* flg       = (unsigned*)(ws + FLG_OFF);
  int* boot           = (int*)(ws + BOOT_OFF);

  init_kernel<<<96, 256, 0, stream>>>(flg, boot);
  xproj_gemm<<<1024, 256, 0, stream>>>(x, w_ih, b_ih, b_hh, xps);
  fused_scan<<<NLAUNCH, 256, 0, stream>>>(xps, w_hh,
      w_ih + (size_t)HID * HID, w_hh + (size_t)HID * HID,
      b_ih + HID, b_hh + HID, h0b, h1b, out, flg, boot);
}